// Round 8
// baseline (2278.767 us; speedup 1.0000x reference)
//
#include <hip/hip_runtime.h>
#include <math.h>

typedef __attribute__((ext_vector_type(8))) short bf16x8;
typedef __attribute__((ext_vector_type(4))) float floatx4;
typedef __attribute__((ext_vector_type(4))) unsigned short ushort4v;
typedef __attribute__((ext_vector_type(8))) unsigned short ushort8v;

typedef __attribute__((address_space(1))) void as1_void;
typedef __attribute__((address_space(3))) void as3_void;

static __device__ __forceinline__ unsigned short f2b(float f) {
    union { float f; unsigned u; } v; v.f = f;
    unsigned r = v.u + 0x7fffu + ((v.u >> 16) & 1u);
    return (unsigned short)(r >> 16);
}
static __device__ __forceinline__ float b2f(unsigned short h) {
    union { unsigned u; float f; } v; v.u = ((unsigned)h) << 16;
    return v.f;
}

template<int P> __device__ __forceinline__ void waitcnt_vm() {
    if constexpr (P == 0)      asm volatile("s_waitcnt vmcnt(0)" ::: "memory");
    else if constexpr (P == 2) asm volatile("s_waitcnt vmcnt(2)" ::: "memory");
    else if constexpr (P == 4) asm volatile("s_waitcnt vmcnt(4)" ::: "memory");
    else                       asm volatile("s_waitcnt vmcnt(6)" ::: "memory");
}

// ---------------------------------------------------------------------------
// gemm9: BK=64, 16-MFMA phases, dbuf-2, 8 waves (2M x 4N). (r5/r7 verified,
// best measured config: FFN-w1 170us / 404 TF effective.)
// C = A(bf16 [M][K], lda) x Bt(bf16 [N][K], ldb)^T, fp32 accumulate.
// Per-wave output (TM/2) x (TN/4). LDS chunk-major [slot][kc(8)][row][8]
// (conflict-free ds_read_b128 + linear global_load_lds dest, 0 bank
// conflicts all session). Phases per K-step: MH*NH quadrants in snake
// order, each = FMp x FNp x 2(ks) = 16 MFMA. Per phase: {ds_read only NEW
// frags; issue staging subset of tile kt+1; s_barrier; lgkmcnt(0);
// setprio(1); 16 MFMA; setprio(0)}.
// Staging: wave w stages kc=w (A at phase 0, B at phase 1) into slot c^1
// (its readers, kt-1's phases, drained before kt began).
// Boundary: vmcnt(0)+barrier — drain distance >= 2 phases so it's cheap.
// k-order per acc element: ks=0,1 within K-step, K-steps ascending ->
// bitwise-identical across all session variants.
// mode 0: Cf = acc+bias | 1: Cf += acc+bias | 2: Cb = bf16(acc+bias)
// mode 3: Cb = bf16(gelu_exact(acc+bias))
// mode 4: Cb = bf16(mask[gc]==0 ? -3e38 : acc*0.0625)   (bias = mask row)
//   NOTE: pow2 scale commutes exactly with bf16 rounding, so mode-4 values
//   equal the old pipeline's b2f(bf16(acc))*0.0625 bitwise.
// Grid: (N/TN, M/TM, Z), block 512. K % 64 == 0.
// ---------------------------------------------------------------------------
template<int TM, int TN>
__global__ __launch_bounds__(512, 2) void gemm9(
    const unsigned short* __restrict__ A,
    const unsigned short* __restrict__ Bt,
    float* __restrict__ Cf, unsigned short* __restrict__ Cb,
    const float* __restrict__ bias,
    int K, int lda, int ldb, int ldc,
    int zdiv, long a_s1, long a_s2, long b_s1, long b_s2, long c_s1, long c_s2,
    int mode)
{
    constexpr int FM  = TM / 32;           // frags per wave, M (4 or 8)
    constexpr int FN  = TN / 64;           // frags per wave, N (2 or 4)
    constexpr int MH  = (FM == 8) ? 2 : 1; // m-halves
    constexpr int NH  = (FN == 4) ? 2 : 1; // n-halves
    constexpr int NPH = MH * NH;           // phases per K-step (2 or 4)
    constexpr int FMp = FM / MH;           // 4
    constexpr int FNp = FN / NH;           // 2
    constexpr int NRA = TM / 64;           // A staging loads per wave per tile
    constexpr int NRB = TN / 64;           // B staging loads per wave per tile

    __shared__ unsigned short As[2][8 * TM * 8];
    __shared__ unsigned short Bs[2][8 * TN * 8];

    const int tid  = threadIdx.x;
    const int wid  = tid >> 6;     // 0..7
    const int lane = tid & 63;
    const int q    = lane >> 4;
    const int r    = lane & 15;
    const int wm   = wid >> 2;     // 0..1
    const int wn   = wid & 3;      // 0..3

    const int z  = blockIdx.z;
    const int zq = z / zdiv, zr = z % zdiv;
    const long offC = (long)zq * c_s1 + (long)zr * c_s2;

    const int m0 = blockIdx.y * TM;
    const int n0 = blockIdx.x * TN;

    const unsigned short* Ab = A  + (long)zq * a_s1 + (long)zr * a_s2 + (long)m0 * lda;
    const unsigned short* Bb = Bt + (long)zq * b_s1 + (long)zr * b_s2 + (long)n0 * ldb;

    floatx4 acc[FM][FN];
    #pragma unroll
    for (int i = 0; i < FM; ++i)
        #pragma unroll
        for (int j = 0; j < FN; ++j)
            acc[i][j] = (floatx4){0.f, 0.f, 0.f, 0.f};

    const int nk = K >> 6;

    // wave `wid` stages k-chunk kc=wid; LDS dest wave-uniform + lane*16B
    auto stageA = [&](int kt, int slot) {
        const int kofs = (kt << 6) + (wid << 3);
        #pragma unroll
        for (int rb = 0; rb < NRA; ++rb)
            __builtin_amdgcn_global_load_lds(
                (as1_void*)(void*)(Ab + (long)(rb * 64 + lane) * lda + kofs),
                (as3_void*)&As[slot][(wid * TM + rb * 64) * 8], 16, 0, 0);
    };
    auto stageB = [&](int kt, int slot) {
        const int kofs = (kt << 6) + (wid << 3);
        #pragma unroll
        for (int rb = 0; rb < NRB; ++rb)
            __builtin_amdgcn_global_load_lds(
                (as1_void*)(void*)(Bb + (long)(rb * 64 + lane) * ldb + kofs),
                (as3_void*)&Bs[slot][(wid * TN + rb * 64) * 8], 16, 0, 0);
    };

    // prologue: stage tile 0 into slot 0, drain, barrier
    stageA(0, 0);
    stageB(0, 0);
    waitcnt_vm<0>();
    asm volatile("s_barrier" ::: "memory");

    for (int kt = 0; kt < nk; ++kt) {
        const int c  = kt & 1;
        const int sl = c ^ 1;
        const bool pf = (kt + 1 < nk);

        bf16x8 af[MH][FMp][2];   // [m-half][frag][ks]
        bf16x8 bf_[NH][FNp][2];  // [n-half][frag][ks]

        #pragma unroll
        for (int ph = 0; ph < NPH; ++ph) {
            const int mh = (MH == 1) ? 0 : ((NPH == 4) ? (ph >> 1) : ph);
            const int nh = (NH == 1) ? 0 : ((NPH == 4) ? (((ph + 1) >> 1) & 1) : ph);
            const bool readA = (ph == mh * (NPH / MH));
            const bool readB = (ph == nh);

            if (readA) {
                #pragma unroll
                for (int i = 0; i < FMp; ++i)
                    #pragma unroll
                    for (int ks = 0; ks < 2; ++ks)
                        af[mh][i][ks] = *(const bf16x8*)&As[c][
                            ((ks * 4 + q) * TM + wm * (TM / 2) + mh * (FMp * 16) + i * 16 + r) * 8];
            }
            if (readB) {
                #pragma unroll
                for (int j = 0; j < FNp; ++j)
                    #pragma unroll
                    for (int ks = 0; ks < 2; ++ks)
                        bf_[nh][j][ks] = *(const bf16x8*)&Bs[c][
                            ((ks * 4 + q) * TN + wn * (TN / 4) + nh * (FNp * 16) + j * 16 + r) * 8];
            }
            if (ph == 0 && pf) stageA(kt + 1, sl);
            if (ph == 1 && pf) stageB(kt + 1, sl);

            asm volatile("s_barrier" ::: "memory");
            asm volatile("s_waitcnt lgkmcnt(0)" ::: "memory");
            __builtin_amdgcn_s_setprio(1);
            #pragma unroll
            for (int i = 0; i < FMp; ++i)
                #pragma unroll
                for (int j = 0; j < FNp; ++j) {
                    acc[mh * FMp + i][nh * FNp + j] = __builtin_amdgcn_mfma_f32_16x16x32_bf16(
                        af[mh][i][0], bf_[nh][j][0], acc[mh * FMp + i][nh * FNp + j], 0, 0, 0);
                    acc[mh * FMp + i][nh * FNp + j] = __builtin_amdgcn_mfma_f32_16x16x32_bf16(
                        af[mh][i][1], bf_[nh][j][1], acc[mh * FMp + i][nh * FNp + j], 0, 0, 0);
                }
            __builtin_amdgcn_s_setprio(0);
        }

        // K-step boundary: tile kt+1 (staged during this step) must be fully
        // resident; drain distance >= 2 phases so this is cheap.
        if (pf) {
            waitcnt_vm<0>();
            asm volatile("s_barrier" ::: "memory");
        }
    }

    // C layout per frag: row = q*4 + reg, col = r (verified m89/m91)
    #pragma unroll
    for (int i = 0; i < FM; ++i) {
        const int gr0 = m0 + wm * (TM / 2) + i * 16 + q * 4;
        #pragma unroll
        for (int j = 0; j < FN; ++j) {
            const int gc = n0 + wn * (TN / 4) + j * 16 + r;
            float bvl = 0.0f, mval = 1.0f;
            if (mode == 4) mval = bias[gc];
            else if (bias) bvl = bias[gc];
            #pragma unroll
            for (int rr = 0; rr < 4; ++rr) {
                const long cidx = offC + (long)(gr0 + rr) * ldc + gc;
                float v = acc[i][j][rr] + bvl;
                if (mode == 0) {
                    Cf[cidx] = v;
                } else if (mode == 1) {
                    Cf[cidx] += v;
                } else if (mode == 2) {
                    Cb[cidx] = f2b(v);
                } else if (mode == 3) {
                    Cb[cidx] = f2b(0.5f * v * (1.0f + erff(v * 0.70710678118654752f)));
                } else {
                    Cb[cidx] = f2b(mval == 0.0f ? -3.0e38f : v * 0.0625f);
                }
            }
        }
    }
}

// ---------------------------------------------------------------------------
// pv_fused: P@V with in-kernel two-pass softmax over raw masked/scaled
// scores (bf16, written by gemm9 mode 4). Per block: 32 q-rows x one head's
// 256 d-cols; grid (64, 4) per batch; 512 threads = 8 waves (2M x 4N).
// Phase 1: per-row max (f32, order-independent) + inv-sum of expf (f32; add
// order differs from the old softmax kernel only at ulp level).
// K-loop: dbuf-2, BK=64, gemm64 cadence (1 barrier/K-step, 8 MFMA/wave).
// A' = bf16(expf(v-mx)*inv) recomputed per element — the exact expression
// the old softmax kernel stored, so PV operands match the old pipeline.
// Staging ledger: slot c^1 written at iter kt (A' ds_write + B
// global_load_lds); its readers (iter kt-1) drained by that iter's
// lgkmcnt(0) before its end barrier. Reads of slot c at iter kt are gated
// by end-of-(kt-1) lgkm0+vmcnt(0)+barrier (all writes of slot c retired
// block-wide). A'-raw global load issued BEFORE the MFMA cluster so its
// latency hides under compute; compiler inserts the dependent waitcnt.
// LDS: 2x(4KB A' + 32KB B) + stats = 72.3 KB.
// ---------------------------------------------------------------------------
__global__ __launch_bounds__(512) void pv_fused(
    const unsigned short* __restrict__ P,    // [4][2048][2048] raw scores
    const unsigned short* __restrict__ vT,   // [4][256][2048]
    unsigned short* __restrict__ O)          // [2048][1024], col = head*256+d
{
    __shared__ unsigned short Ap[2][8][32][8];    // 4KB per slot
    __shared__ unsigned short Bs[2][8][256][8];   // 32KB per slot
    __shared__ float smax[32], sinv[32];

    const int tid  = threadIdx.x;
    const int wid  = tid >> 6, lane = tid & 63;
    const int q    = lane >> 4, r = lane & 15;
    const int wm   = wid >> 2;    // 0..1: rows wm*16
    const int wn   = wid & 3;     // 0..3: d-cols wn*64
    const int m0   = blockIdx.x * 32;
    const int hh   = blockIdx.y;

    const unsigned short* Pa = P  + (long)hh * 4194304 + (long)m0 * 2048;
    const unsigned short* Bb = vT + (long)hh * 524288;

    // ---- phase 1: row stats (16 threads/row, 128 cols each, regs-cached) ----
    {
        const int row = tid >> 4, sub = tid & 15;
        const unsigned short* rp = Pa + (long)row * 2048 + sub * 128;
        ushort8v buf[16];
        #pragma unroll
        for (int i = 0; i < 16; ++i) buf[i] = *(const ushort8v*)&rp[i * 8];
        float mx = -3.0e38f;
        #pragma unroll
        for (int i = 0; i < 16; ++i)
            #pragma unroll
            for (int e = 0; e < 8; ++e) mx = fmaxf(mx, b2f(buf[i][e]));
        #pragma unroll
        for (int off = 8; off > 0; off >>= 1) mx = fmaxf(mx, __shfl_xor(mx, off));
        float s = 0.0f;
        #pragma unroll
        for (int i = 0; i < 16; ++i)
            #pragma unroll
            for (int e = 0; e < 8; ++e) s += expf(b2f(buf[i][e]) - mx);
        #pragma unroll
        for (int off = 8; off > 0; off >>= 1) s += __shfl_xor(s, off);
        if (sub == 0) { smax[row] = mx; sinv[row] = (s > 0.0f) ? 1.0f / s : 0.0f; }
    }
    __syncthreads();

    // staging role: thread stages A'[arow][kc=wid*8 + kh*4 .. +4]
    const int arow = lane >> 1;
    const int kh   = lane & 1;
    const float mxr = smax[arow];
    const float ivr = sinv[arow];
    const unsigned short* Asrc = Pa + (long)arow * 2048 + wid * 8 + kh * 4;

    auto stageB = [&](int kt, int slot) {
        const int kofs = (kt << 6) + (wid << 3);
        #pragma unroll
        for (int rb = 0; rb < 4; ++rb)
            __builtin_amdgcn_global_load_lds(
                (as1_void*)(void*)(Bb + (long)(rb * 64 + lane) * 2048 + kofs),
                (as3_void*)&Bs[slot][wid][rb * 64][0], 16, 0, 0);
    };
    auto xformA = [&](ushort4v raw, int slot) {
        ushort4v pw;
        #pragma unroll
        for (int e = 0; e < 4; ++e)
            pw[e] = f2b(expf(b2f(raw[e]) - mxr) * ivr);
        *(ushort4v*)&Ap[slot][wid][arow][kh * 4] = pw;
    };

    floatx4 acc[4];
    #pragma unroll
    for (int j = 0; j < 4; ++j) acc[j] = (floatx4){0.f, 0.f, 0.f, 0.f};

    // prologue: fill slot 0
    {
        const ushort4v raw0 = *(const ushort4v*)&Asrc[0];
        stageB(0, 0);
        xformA(raw0, 0);
        asm volatile("s_waitcnt lgkmcnt(0)" ::: "memory");
        asm volatile("s_waitcnt vmcnt(0)" ::: "memory");
        asm volatile("s_barrier" ::: "memory");
    }

    for (int kt = 0; kt < 32; ++kt) {
        const int c = kt & 1;
        const bool pf = (kt + 1 < 32);

        ushort4v raw;
        if (pf) {
            raw = *(const ushort4v*)&Asrc[(kt + 1) << 6];   // early issue
            stageB(kt + 1, c ^ 1);
        }

        bf16x8 av[2], bv[4][2];
        #pragma unroll
        for (int ks = 0; ks < 2; ++ks)
            av[ks] = *(const bf16x8*)&Ap[c][ks * 4 + q][wm * 16 + r][0];
        #pragma unroll
        for (int j = 0; j < 4; ++j)
            #pragma unroll
            for (int ks = 0; ks < 2; ++ks)
                bv[j][ks] = *(const bf16x8*)&Bs[c][ks * 4 + q][wn * 64 + j * 16 + r][0];
        asm volatile("s_waitcnt lgkmcnt(0)" ::: "memory");

        __builtin_amdgcn_s_setprio(1);
        #pragma unroll
        for (int j = 0; j < 4; ++j) {
            acc[j] = __builtin_amdgcn_mfma_f32_16x16x32_bf16(av[0], bv[j][0], acc[j], 0, 0, 0);
            acc[j] = __builtin_amdgcn_mfma_f32_16x16x32_bf16(av[1], bv[j][1], acc[j], 0, 0, 0);
        }
        __builtin_amdgcn_s_setprio(0);

        if (pf) {
            xformA(raw, c ^ 1);                               // exp + ds_write
            asm volatile("s_waitcnt lgkmcnt(0)" ::: "memory"); // ds_write + frag reads drained
            asm volatile("s_waitcnt vmcnt(0)" ::: "memory");   // B tile resident
            asm volatile("s_barrier" ::: "memory");
        }
    }

    // C layout per frag: row = q*4 + rr, col = r
    const int gr0 = m0 + wm * 16 + q * 4;
    #pragma unroll
    for (int j = 0; j < 4; ++j) {
        const int gc = hh * 256 + wn * 64 + j * 16 + r;
        #pragma unroll
        for (int rr = 0; rr < 4; ++rr)
            O[(long)(gr0 + rr) * 1024 + gc] = f2b(acc[j][rr]);
    }
}

// fp32 [R][C] -> bf16 [C][R], 32x32 LDS tile transpose
__global__ void transpose_cast_f32(const float* __restrict__ in, unsigned short* __restrict__ out,
                                   int R, int C)
{
    __shared__ float t[32][33];
    const int c0 = blockIdx.x * 32, r0 = blockIdx.y * 32;
    const int tx = threadIdx.x, ty = threadIdx.y;
    #pragma unroll
    for (int i = 0; i < 4; ++i)
        t[ty + i * 8][tx] = in[(long)(r0 + ty + i * 8) * C + c0 + tx];
    __syncthreads();
    #pragma unroll
    for (int i = 0; i < 4; ++i)
        out[(long)(c0 + ty + i * 8) * R + r0 + tx] = f2b(t[tx][ty + i * 8]);
}

// V slice of qkv_b [2048][3072] (cols 2048 + h*256 + d) -> vT [h][d][m]
__global__ void transpose_v(const unsigned short* __restrict__ qkv, unsigned short* __restrict__ vT)
{
    __shared__ unsigned short t[32][33];
    const int hh = blockIdx.z;
    const int d0 = blockIdx.x * 32, m0 = blockIdx.y * 32;
    const int tx = threadIdx.x, ty = threadIdx.y;
    const unsigned short* ip = qkv + 2048 + hh * 256;
    unsigned short* op = vT + (long)hh * 524288;
    #pragma unroll
    for (int i = 0; i < 4; ++i)
        t[ty + i * 8][tx] = ip[(long)(m0 + ty + i * 8) * 3072 + d0 + tx];
    __syncthreads();
    #pragma unroll
    for (int i = 0; i < 4; ++i)
        op[(long)(d0 + ty + i * 8) * 2048 + m0 + tx] = t[tx][ty + i * 8];
}

__global__ void cast_f32_bf16(const float* __restrict__ in, unsigned short* __restrict__ out)
{
    const long i = (long)blockIdx.x * 256 + threadIdx.x;   // one float4 each
    const float4 v = ((const float4*)in)[i];
    ushort4v o;
    o[0] = f2b(v.x); o[1] = f2b(v.y); o[2] = f2b(v.z); o[3] = f2b(v.w);
    ((ushort4v*)out)[i] = o;
}

__global__ void zero_f32(float* __restrict__ p)
{
    p[blockIdx.x * 256 + threadIdx.x] = 0.0f;
}

// LayerNorm over D=1024, one block per token, writes bf16
__global__ __launch_bounds__(256) void ln_kernel(const float* __restrict__ h,
    const float* __restrict__ g, const float* __restrict__ bta,
    unsigned short* __restrict__ out)
{
    const int tok = blockIdx.x;
    const float4 v = ((const float4*)(h + (long)tok * 1024))[threadIdx.x];
    float s  = v.x + v.y + v.z + v.w;
    float s2 = v.x * v.x + v.y * v.y + v.z * v.z + v.w * v.w;
    #pragma unroll
    for (int off = 32; off > 0; off >>= 1) {
        s  += __shfl_xor(s, off);
        s2 += __shfl_xor(s2, off);
    }
    __shared__ float rs[4], rs2[4];
    const int wid = threadIdx.x >> 6, lane = threadIdx.x & 63;
    if (lane == 0) { rs[wid] = s; rs2[wid] = s2; }
    __syncthreads();
    s  = rs[0] + rs[1] + rs[2] + rs[3];
    s2 = rs2[0] + rs2[1] + rs2[2] + rs2[3];
    const float mu = s * (1.0f / 1024.0f);
    float var = s2 * (1.0f / 1024.0f) - mu * mu;
    var = fmaxf(var, 0.0f);
    const float rsg = 1.0f / sqrtf(var + 1e-5f);
    const float4 gv = ((const float4*)g)[threadIdx.x];
    const float4 bv = ((const float4*)bta)[threadIdx.x];
    ushort4v o;
    o[0] = f2b((v.x - mu) * rsg * gv.x + bv.x);
    o[1] = f2b((v.y - mu) * rsg * gv.y + bv.y);
    o[2] = f2b((v.z - mu) * rsg * gv.z + bv.z);
    o[3] = f2b((v.w - mu) * rsg * gv.w + bv.w);
    *(ushort4v*)&out[(long)tok * 1024 + threadIdx.x * 4] = o;
}

// RoPE in-place on bf16 qkv_b [2048][3072] (q: 0..1023, k: 1024..2047)
__global__ __launch_bounds__(256) void rope_kernel(unsigned short* __restrict__ qkv,
                                                   const int* __restrict__ pos)
{
    const int tok = blockIdx.x;
    const float p = (float)pos[tok];
    unsigned short* base = qkv + (long)tok * 3072;
    #pragma unroll
    for (int it = 0; it < 2; ++it) {
        const int idx = threadIdx.x + it * 256;  // (head, d<128)
        const int hh = idx >> 7, d = idx & 127;
        const float inv = exp2f((float)d * (-13.287712379549449f / 128.0f));
        const float ang = p * inv;
        const float c = cosf(ang), s = sinf(ang);
        unsigned short* qp = base + hh * 256 + d;
        {
            const float x1 = b2f(qp[0]), x2 = b2f(qp[128]);
            qp[0]   = f2b(x1 * c - x2 * s);
            qp[128] = f2b(x1 * s + x2 * c);
        }
        unsigned short* kp = qp + 1024;
        {
            const float x1 = b2f(kp[0]), x2 = b2f(kp[128]);
            kp[0]   = f2b(x1 * c - x2 * s);
            kp[128] = f2b(x1 * s + x2 * c);
        }
    }
}

// lengths = sum(mask[b]); out[b] = len>0 ? h[b, len-1] : start_state
__global__ __launch_bounds__(256) void gather_kernel(const float* __restrict__ h,
    const float* __restrict__ mask, const float* __restrict__ ss, float* __restrict__ out)
{
    const int b = blockIdx.x;
    const float* mrow = mask + b * 2048;
    const int t = threadIdx.x;
    float s = 0.0f;
    #pragma unroll
    for (int i = 0; i < 8; ++i) s += mrow[t * 8 + i];
    #pragma unroll
    for (int off = 32; off > 0; off >>= 1) s += __shfl_xor(s, off);
    __shared__ float red[4];
    if ((t & 63) == 0) red[t >> 6] = s;
    __syncthreads();
    const float len = red[0] + red[1] + red[2] + red[3];
    const int L = (int)len;
    const int last = (L > 0) ? (L - 1) : 0;
    const bool has = len > 0.0f;
    const float* src = has ? (h + ((long)b * 2048 + last) * 1024) : ss;
    #pragma unroll
    for (int i = 0; i < 4; ++i) {
        const int d = t + i * 256;
        out[b * 1024 + d] = src[d];
    }
}

// ---------------------------------------------------------------------------
extern "C" void kernel_launch(void* const* d_in, const int* in_sizes, int n_in,
                              void* d_out, int out_size, void* d_ws, size_t ws_size,
                              hipStream_t stream)
{
    (void)in_sizes; (void)n_in; (void)out_size;
    const float* x      = (const float*)d_in[0];
    const int*   pos    = (const int*)d_in[1];
    const float* mask   = (const float*)d_in[2];
    const float* in_w   = (const float*)d_in[3];
    const float* in_b   = (const float*)d_in[4];
    const float* qkv_w  = (const float*)d_in[5];
    const float* o_w    = (const float*)d_in[6];
    const float* ln1_g  = (const float*)d_in[7];
    const float* ln1_b  = (const float*)d_in[8];
    const float* ffn_w1 = (const float*)d_in[9];
    const float* ffn_b1 = (const float*)d_in[10];
    const float* ffn_w2 = (const float*)d_in[11];
    const float* ffn_b2 = (const float*)d_in[12];
    const float* ln2_g  = (const float*)d_in[13];
    const float* ln2_b  = (const float*)d_in[14];
    const float* sstate = (const float*)d_in[15];
    float* out = (float*)d_out;

    // ---- workspace layout, 143.65 MB (proven safe) ----
    const size_t NEED = 143654912ull;
    if (ws_size < NEED) {
        zero_f32<<<16, 256, 0, stream>>>(out);
        return;
    }
    char* w = (char*)d_ws;
    unsigned short* wt_in  = (unsigned short*)(w);               // [1024][512]      1.0 MB
    unsigned short* wt_qkv = (unsigned short*)(w + 1048576);     // [3072][1024]/lyr 6.3 MB
    unsigned short* wt_o   = (unsigned short*)(w + 7340032);     // [1024][1024]/lyr 2.1 MB
    unsigned short* wt_f1  = (unsigned short*)(w + 9437184);     // [4096][1024]/lyr 8.4 MB
    unsigned short* wt_f2  = (unsigned short*)(w + 17825792);    // [1024][4096]/lyr 8.4 MB
    float*          hbuf   = (float*)(w + 26214400);             // [8192][1024] f32 33.5 MB
    unsigned short* xn_bf  = (unsigned short*)(w + 59768832);    // [8192][1024]     16.8 MB
    unsigned short* ao_bf  = (unsigned short*)(w + 76546048);    // [8192][1024]     16.8 MB
    unsigned short* qkv_b  = (unsigned short*)(w + 93323264);    // [2048][3072]/b   12.6 MB
    unsigned short* vT_b   = (unsigned short*)(w + 105906176);   // [4][256][2048]/b  4.2 MB
    unsigned short* scmid  = (unsigned short*)(w + 110100480);   // [4][2048][2048]  33.5 MB
    unsigned short* x_bf   = ao_bf;                              // [8192][512], dead before ao live
    unsigned short* mid_bf = (unsigned short*)(w + 76546048);    // FFN mid aliases ao/qkv/vT/scmid

    const dim3 tb(32, 8);

    transpose_cast_f32<<<dim3(32, 16), tb, 0, stream>>>(in_w, wt_in, 512, 1024);
    cast_f32_bf16<<<4096, 256, 0, stream>>>(x, x_bf);

    // h = x @ in_w + in_b   (f32)  M=8192 N=1024 K=512 — 256 blocks
    gemm9<256, 128><<<dim3(8, 32, 1), 512, 0, stream>>>(x_bf, wt_in, hbuf, nullptr, in_b,
        512, 512, 512, 1024, 1, 0, 0, 0, 0, 0, 0, 0);

    for (int l = 0; l < 2; ++l) {
        transpose_cast_f32<<<dim3(96, 32),  tb, 0, stream>>>(qkv_w  + (long)l * 3145728, wt_qkv, 1024, 3072);
        transpose_cast_f32<<<dim3(32, 32),  tb, 0, stream>>>(o_w    + (long)l * 1048576, wt_o,   1024, 1024);
        transpose_cast_f32<<<dim3(128, 32), tb, 0, stream>>>(ffn_w1 + (long)l * 4194304, wt_f1,  1024, 4096);
        transpose_cast_f32<<<dim3(32, 128), tb, 0, stream>>>(ffn_w2 + (long)l * 4194304, wt_f2,  4096, 1024);

        ln_kernel<<<8192, 256, 0, stream>>>(hbuf, ln1_g + l * 1024, ln1_b + l * 1024, xn_bf);

        for (int b = 0; b < 4; ++b) {
            // qkv_b = LN1(h)[b] @ qkv_w  (bf16)  M=2048 N=3072 K=1024 — 192 blocks
            gemm9<128, 256><<<dim3(12, 16, 1), 512, 0, stream>>>(xn_bf + (long)b * 2097152, wt_qkv,
                nullptr, qkv_b, nullptr, 1024, 1024, 1024, 3072, 1, 0, 0, 0, 0, 0, 0, 2);
            rope_kernel<<<2048, 256, 0, stream>>>(qkv_b, pos + b * 2048);
            transpose_v<<<dim3(8, 64, 4), tb, 0, stream>>>(qkv_b, vT_b);
            // scores[h] = bf16(mask ? qk^T/16 : -3e38)  K=256 — 256 blocks (mode 4)
            gemm9<256, 256><<<dim3(8, 8, 4), 512, 0, stream>>>(qkv_b, qkv_b + 1024,
                nullptr, scmid, mask + b * 2048, 256, 3072, 3072, 2048,
                1, 256l, 0, 256l, 0, 4194304l, 0, 4);
            // ao[b] = softmax(scores) @ V — fused two-pass softmax + PV, 256 blocks
            pv_fused<<<dim3(64, 4), 512, 0, stream>>>(scmid, vT_b, ao_bf + (long)b * 2097152);
        }
        // h += attn_out @ o_w   M=8192 N=1024 K=1024 — 256 blocks
        gemm9<256, 128><<<dim3(8, 32, 1), 512, 0, stream>>>(ao_bf, wt_o,
            hbuf, nullptr, nullptr, 1024, 1024, 1024, 1024, 1, 0, 0, 0, 0, 0, 0, 1);

        ln_kernel<<<8192, 256, 0, stream>>>(hbuf, ln2_g + l * 1024, ln2_b + l * 1024, xn_bf);

        // mid = gelu(LN2(h) @ w1 + b1)  (bf16)  M=8192 N=4096 K=1024 — 512 blocks
        gemm9<256, 256><<<dim3(16, 32, 1), 512, 0, stream>>>(xn_bf, wt_f1,
            nullptr, mid_bf, ffn_b1 + l * 4096, 1024, 1024, 1024, 4096, 1, 0, 0, 0, 0, 0, 0, 3);
        // h += mid @ w2 + b2   M=8192 N=1024 K=4096 — 256 blocks
        gemm9<256, 128><<<dim3(8, 32, 1), 512, 0, stream>>>(mid_bf, wt_f2,
            hbuf, nullptr, ffn_b2 + l * 1024, 4096, 4096, 4096, 1024, 1, 0, 0, 0, 0, 0, 0, 1);
    }

    gather_kernel<<<4, 256, 0, stream>>>(hbuf, mask, sstate, out);
}

// Round 9
// 2047.194 us; speedup vs baseline: 1.1131x; 1.1131x over previous
//
#include <hip/hip_runtime.h>
#include <math.h>

typedef __attribute__((ext_vector_type(8))) short bf16x8;
typedef __attribute__((ext_vector_type(4))) float floatx4;
typedef __attribute__((ext_vector_type(4))) unsigned short ushort4v;

typedef __attribute__((address_space(1))) void as1_void;
typedef __attribute__((address_space(3))) void as3_void;

static __device__ __forceinline__ unsigned short f2b(float f) {
    union { float f; unsigned u; } v; v.f = f;
    unsigned r = v.u + 0x7fffu + ((v.u >> 16) & 1u);
    return (unsigned short)(r >> 16);
}
static __device__ __forceinline__ float b2f(unsigned short h) {
    union { unsigned u; float f; } v; v.u = ((unsigned)h) << 16;
    return v.f;
}

template<int P> __device__ __forceinline__ void waitcnt_vm() {
    if constexpr (P == 0)      asm volatile("s_waitcnt vmcnt(0)" ::: "memory");
    else if constexpr (P == 2) asm volatile("s_waitcnt vmcnt(2)" ::: "memory");
    else if constexpr (P == 4) asm volatile("s_waitcnt vmcnt(4)" ::: "memory");
    else                       asm volatile("s_waitcnt vmcnt(6)" ::: "memory");
}

// ---------------------------------------------------------------------------
// gemm9: BK=64, 16-MFMA phases, dbuf-2, 8 waves (2M x 4N). (r5/r7 verified,
// best measured config: FFN-w1 170us / 404 TF effective.)
// C = A(bf16 [M][K], lda) x Bt(bf16 [N][K], ldb)^T, fp32 accumulate.
// Per-wave output (TM/2) x (TN/4). LDS chunk-major [slot][kc(8)][row][8]
// (conflict-free ds_read_b128 + linear global_load_lds dest, 0 bank
// conflicts all session). Phases per K-step: MH*NH quadrants in snake
// order, each = FMp x FNp x 2(ks) = 16 MFMA. Per phase: {ds_read only NEW
// frags; issue staging subset of tile kt+1; s_barrier; lgkmcnt(0);
// setprio(1); 16 MFMA; setprio(0)}.
// Staging: wave w stages kc=w (A at phase 0, B at phase 1) into slot c^1
// (its readers, kt-1's phases, drained before kt began).
// Boundary: vmcnt(0)+barrier — drain distance >= 2 phases so it's cheap.
// k-order per acc element: ks=0,1 within K-step, K-steps ascending ->
// bitwise-identical across all session variants.
// mode 0: Cf = acc+bias | 1: Cf += acc+bias | 2: Cb = bf16(acc+bias)
// mode 3: Cb = bf16(gelu_exact(acc+bias))
// mode 5: qkv split-write — gc<2048: Cb[cidx]=bf16(acc) (Q,K region);
//         gc>=2048: one 8B store of 4 row-contiguous bf16 into
//         Vt[(gc-2048)*2048 + gr0] (Vt passed via Cf). Values are the same
//         f2b(acc) transpose_v previously copied verbatim -> bitwise-same vT.
// Grid: (N/TN, M/TM, Z), block 512. K % 64 == 0.
// ---------------------------------------------------------------------------
template<int TM, int TN>
__global__ __launch_bounds__(512, 2) void gemm9(
    const unsigned short* __restrict__ A,
    const unsigned short* __restrict__ Bt,
    float* __restrict__ Cf, unsigned short* __restrict__ Cb,
    const float* __restrict__ bias,
    int K, int lda, int ldb, int ldc,
    int zdiv, long a_s1, long a_s2, long b_s1, long b_s2, long c_s1, long c_s2,
    int mode)
{
    constexpr int FM  = TM / 32;           // frags per wave, M (4 or 8)
    constexpr int FN  = TN / 64;           // frags per wave, N (2 or 4)
    constexpr int MH  = (FM == 8) ? 2 : 1; // m-halves
    constexpr int NH  = (FN == 4) ? 2 : 1; // n-halves
    constexpr int NPH = MH * NH;           // phases per K-step (2 or 4)
    constexpr int FMp = FM / MH;           // 4
    constexpr int FNp = FN / NH;           // 2
    constexpr int NRA = TM / 64;           // A staging loads per wave per tile
    constexpr int NRB = TN / 64;           // B staging loads per wave per tile

    __shared__ unsigned short As[2][8 * TM * 8];
    __shared__ unsigned short Bs[2][8 * TN * 8];

    const int tid  = threadIdx.x;
    const int wid  = tid >> 6;     // 0..7
    const int lane = tid & 63;
    const int q    = lane >> 4;
    const int r    = lane & 15;
    const int wm   = wid >> 2;     // 0..1
    const int wn   = wid & 3;      // 0..3

    const int z  = blockIdx.z;
    const int zq = z / zdiv, zr = z % zdiv;
    const long offC = (long)zq * c_s1 + (long)zr * c_s2;

    const int m0 = blockIdx.y * TM;
    const int n0 = blockIdx.x * TN;

    const unsigned short* Ab = A  + (long)zq * a_s1 + (long)zr * a_s2 + (long)m0 * lda;
    const unsigned short* Bb = Bt + (long)zq * b_s1 + (long)zr * b_s2 + (long)n0 * ldb;

    floatx4 acc[FM][FN];
    #pragma unroll
    for (int i = 0; i < FM; ++i)
        #pragma unroll
        for (int j = 0; j < FN; ++j)
            acc[i][j] = (floatx4){0.f, 0.f, 0.f, 0.f};

    const int nk = K >> 6;

    // wave `wid` stages k-chunk kc=wid; LDS dest wave-uniform + lane*16B
    auto stageA = [&](int kt, int slot) {
        const int kofs = (kt << 6) + (wid << 3);
        #pragma unroll
        for (int rb = 0; rb < NRA; ++rb)
            __builtin_amdgcn_global_load_lds(
                (as1_void*)(void*)(Ab + (long)(rb * 64 + lane) * lda + kofs),
                (as3_void*)&As[slot][(wid * TM + rb * 64) * 8], 16, 0, 0);
    };
    auto stageB = [&](int kt, int slot) {
        const int kofs = (kt << 6) + (wid << 3);
        #pragma unroll
        for (int rb = 0; rb < NRB; ++rb)
            __builtin_amdgcn_global_load_lds(
                (as1_void*)(void*)(Bb + (long)(rb * 64 + lane) * ldb + kofs),
                (as3_void*)&Bs[slot][(wid * TN + rb * 64) * 8], 16, 0, 0);
    };

    // prologue: stage tile 0 into slot 0, drain, barrier
    stageA(0, 0);
    stageB(0, 0);
    waitcnt_vm<0>();
    asm volatile("s_barrier" ::: "memory");

    for (int kt = 0; kt < nk; ++kt) {
        const int c  = kt & 1;
        const int sl = c ^ 1;
        const bool pf = (kt + 1 < nk);

        bf16x8 af[MH][FMp][2];   // [m-half][frag][ks]
        bf16x8 bf_[NH][FNp][2];  // [n-half][frag][ks]

        #pragma unroll
        for (int ph = 0; ph < NPH; ++ph) {
            const int mh = (MH == 1) ? 0 : ((NPH == 4) ? (ph >> 1) : ph);
            const int nh = (NH == 1) ? 0 : ((NPH == 4) ? (((ph + 1) >> 1) & 1) : ph);
            const bool readA = (ph == mh * (NPH / MH));
            const bool readB = (ph == nh);

            if (readA) {
                #pragma unroll
                for (int i = 0; i < FMp; ++i)
                    #pragma unroll
                    for (int ks = 0; ks < 2; ++ks)
                        af[mh][i][ks] = *(const bf16x8*)&As[c][
                            ((ks * 4 + q) * TM + wm * (TM / 2) + mh * (FMp * 16) + i * 16 + r) * 8];
            }
            if (readB) {
                #pragma unroll
                for (int j = 0; j < FNp; ++j)
                    #pragma unroll
                    for (int ks = 0; ks < 2; ++ks)
                        bf_[nh][j][ks] = *(const bf16x8*)&Bs[c][
                            ((ks * 4 + q) * TN + wn * (TN / 4) + nh * (FNp * 16) + j * 16 + r) * 8];
            }
            if (ph == 0 && pf) stageA(kt + 1, sl);
            if (ph == 1 && pf) stageB(kt + 1, sl);

            asm volatile("s_barrier" ::: "memory");
            asm volatile("s_waitcnt lgkmcnt(0)" ::: "memory");
            __builtin_amdgcn_s_setprio(1);
            #pragma unroll
            for (int i = 0; i < FMp; ++i)
                #pragma unroll
                for (int j = 0; j < FNp; ++j) {
                    acc[mh * FMp + i][nh * FNp + j] = __builtin_amdgcn_mfma_f32_16x16x32_bf16(
                        af[mh][i][0], bf_[nh][j][0], acc[mh * FMp + i][nh * FNp + j], 0, 0, 0);
                    acc[mh * FMp + i][nh * FNp + j] = __builtin_amdgcn_mfma_f32_16x16x32_bf16(
                        af[mh][i][1], bf_[nh][j][1], acc[mh * FMp + i][nh * FNp + j], 0, 0, 0);
                }
            __builtin_amdgcn_s_setprio(0);
        }

        // K-step boundary: tile kt+1 (staged during this step) must be fully
        // resident; drain distance >= 2 phases so this is cheap.
        if (pf) {
            waitcnt_vm<0>();
            asm volatile("s_barrier" ::: "memory");
        }
    }

    // C layout per frag: row = q*4 + reg, col = r (verified m89/m91)
    #pragma unroll
    for (int i = 0; i < FM; ++i) {
        const int gr0 = m0 + wm * (TM / 2) + i * 16 + q * 4;
        #pragma unroll
        for (int j = 0; j < FN; ++j) {
            const int gc = n0 + wn * (TN / 4) + j * 16 + r;
            const float bvl = (mode != 5 && bias) ? bias[gc] : 0.0f;
            if (mode == 5) {
                // qkv split-write: Q,K -> Cb; V -> Vt directly (8B store)
                ushort4v pk;
                #pragma unroll
                for (int rr = 0; rr < 4; ++rr) pk[rr] = f2b(acc[i][j][rr]);
                if (gc < 2048) {
                    #pragma unroll
                    for (int rr = 0; rr < 4; ++rr)
                        Cb[offC + (long)(gr0 + rr) * ldc + gc] = pk[rr];
                } else {
                    unsigned short* Vt = (unsigned short*)Cf;
                    *(ushort4v*)&Vt[(long)(gc - 2048) * 2048 + gr0] = pk;
                }
                continue;
            }
            #pragma unroll
            for (int rr = 0; rr < 4; ++rr) {
                const long cidx = offC + (long)(gr0 + rr) * ldc + gc;
                float v = acc[i][j][rr] + bvl;
                if (mode == 0) {
                    Cf[cidx] = v;
                } else if (mode == 1) {
                    Cf[cidx] += v;
                } else if (mode == 2) {
                    Cb[cidx] = f2b(v);
                } else {
                    Cb[cidx] = f2b(0.5f * v * (1.0f + erff(v * 0.70710678118654752f)));
                }
            }
        }
    }
}

// ---------------------------------------------------------------------------
// gemm64: PV GEMM — T=64 tile, BK=64, dbuf-2, 4 waves, 256 threads.
// (r7 verified: ONE boundary per 64-wide K-step, 8 MFMA/wave between
// boundaries, LDS 32KB -> 5 blocks/CU.)
// Ledger: stage at kt targets slot (kt+1)&1, whose readers (iter kt-1)
// drained (lgkmcnt 0) before kt-1's end barrier, which all waves passed
// before any wave issues kt's stage. Reads of tile kt gated by end-of-(kt-1)
// vmcnt(0)+barrier. k-order: kt ascending, ks=0,1 ascending.
// C = A x Bt^T, bf16 out, no bias. Grid (N/64, M/64, Z), block 256.
// ---------------------------------------------------------------------------
__global__ __launch_bounds__(256) void gemm64(
    const unsigned short* __restrict__ A,
    const unsigned short* __restrict__ Bt,
    unsigned short* __restrict__ Cb,
    int K, int lda, int ldb, int ldc,
    long a_s1, long b_s1, long c_s1)
{
    __shared__ unsigned short As[2][8][64][8];   // 8KB per slot
    __shared__ unsigned short Bs[2][8][64][8];

    const int tid  = threadIdx.x;
    const int wid  = tid >> 6;     // 0..3
    const int lane = tid & 63;
    const int q    = lane >> 4;
    const int r    = lane & 15;
    const int wr   = (wid >> 1) * 32;
    const int wc   = (wid & 1) * 32;

    const int z  = blockIdx.z;
    const long offC = (long)z * c_s1;

    const int m0 = blockIdx.y * 64;
    const int n0 = blockIdx.x * 64;

    const unsigned short* Ab = A  + (long)z * a_s1 + (long)m0 * lda;
    const unsigned short* Bb = Bt + (long)z * b_s1 + (long)n0 * ldb;

    floatx4 acc[2][2];
    #pragma unroll
    for (int i = 0; i < 2; ++i)
        #pragma unroll
        for (int j = 0; j < 2; ++j)
            acc[i][j] = (floatx4){0.f, 0.f, 0.f, 0.f};

    const int nk = K >> 6;

    // wave w stages k-chunks {w, w+4} of both tiles (4 loads/wave/tile)
    auto stage = [&](int kt, int slot) {
        #pragma unroll
        for (int cc = 0; cc < 2; ++cc) {
            const int kc   = wid + cc * 4;
            const int kofs = (kt << 6) + (kc << 3);
            __builtin_amdgcn_global_load_lds(
                (as1_void*)(void*)(Ab + (long)lane * lda + kofs),
                (as3_void*)&As[slot][kc][0][0], 16, 0, 0);
            __builtin_amdgcn_global_load_lds(
                (as1_void*)(void*)(Bb + (long)lane * ldb + kofs),
                (as3_void*)&Bs[slot][kc][0][0], 16, 0, 0);
        }
    };

    stage(0, 0);
    waitcnt_vm<0>();
    asm volatile("s_barrier" ::: "memory");

    for (int kt = 0; kt < nk; ++kt) {
        const int c = kt & 1;
        const bool pf = (kt + 1 < nk);
        if (pf) stage(kt + 1, c ^ 1);

        bf16x8 av[2][2], bv[2][2];
        #pragma unroll
        for (int i = 0; i < 2; ++i)
            #pragma unroll
            for (int ks = 0; ks < 2; ++ks)
                av[i][ks] = *(const bf16x8*)&As[c][ks * 4 + q][wr + i * 16 + r][0];
        #pragma unroll
        for (int j = 0; j < 2; ++j)
            #pragma unroll
            for (int ks = 0; ks < 2; ++ks)
                bv[j][ks] = *(const bf16x8*)&Bs[c][ks * 4 + q][wc + j * 16 + r][0];

        __builtin_amdgcn_s_setprio(1);
        #pragma unroll
        for (int i = 0; i < 2; ++i)
            #pragma unroll
            for (int j = 0; j < 2; ++j) {
                acc[i][j] = __builtin_amdgcn_mfma_f32_16x16x32_bf16(av[i][0], bv[j][0], acc[i][j], 0, 0, 0);
                acc[i][j] = __builtin_amdgcn_mfma_f32_16x16x32_bf16(av[i][1], bv[j][1], acc[i][j], 0, 0, 0);
            }
        __builtin_amdgcn_s_setprio(0);

        if (pf) {
            asm volatile("s_waitcnt lgkmcnt(0)" ::: "memory");   // all reads of slot c retired
            waitcnt_vm<0>();                                      // tile kt+1 resident
            asm volatile("s_barrier" ::: "memory");
        }
    }

    // C layout per frag: row = q*4 + reg, col = r (verified m89/m91)
    #pragma unroll
    for (int i = 0; i < 2; ++i) {
        const int gr0 = m0 + wr + i * 16 + q * 4;
        #pragma unroll
        for (int j = 0; j < 2; ++j) {
            const int gc = n0 + wc + j * 16 + r;
            #pragma unroll
            for (int rr = 0; rr < 4; ++rr) {
                const long cidx = offC + (long)(gr0 + rr) * ldc + gc;
                Cb[cidx] = f2b(acc[i][j][rr]);
            }
        }
    }
}

// fp32 [R][C] -> bf16 [C][R], 32x32 LDS tile transpose
__global__ void transpose_cast_f32(const float* __restrict__ in, unsigned short* __restrict__ out,
                                   int R, int C)
{
    __shared__ float t[32][33];
    const int c0 = blockIdx.x * 32, r0 = blockIdx.y * 32;
    const int tx = threadIdx.x, ty = threadIdx.y;
    #pragma unroll
    for (int i = 0; i < 4; ++i)
        t[ty + i * 8][tx] = in[(long)(r0 + ty + i * 8) * C + c0 + tx];
    __syncthreads();
    #pragma unroll
    for (int i = 0; i < 4; ++i)
        out[(long)(c0 + ty + i * 8) * R + r0 + tx] = f2b(t[tx][ty + i * 8]);
}

__global__ void cast_f32_bf16(const float* __restrict__ in, unsigned short* __restrict__ out)
{
    const long i = (long)blockIdx.x * 256 + threadIdx.x;   // one float4 each
    const float4 v = ((const float4*)in)[i];
    ushort4v o;
    o[0] = f2b(v.x); o[1] = f2b(v.y); o[2] = f2b(v.z); o[3] = f2b(v.w);
    ((ushort4v*)out)[i] = o;
}

__global__ void zero_f32(float* __restrict__ p)
{
    p[blockIdx.x * 256 + threadIdx.x] = 0.0f;
}

// LayerNorm over D=1024, one block per token, writes bf16
__global__ __launch_bounds__(256) void ln_kernel(const float* __restrict__ h,
    const float* __restrict__ g, const float* __restrict__ bta,
    unsigned short* __restrict__ out)
{
    const int tok = blockIdx.x;
    const float4 v = ((const float4*)(h + (long)tok * 1024))[threadIdx.x];
    float s  = v.x + v.y + v.z + v.w;
    float s2 = v.x * v.x + v.y * v.y + v.z * v.z + v.w * v.w;
    #pragma unroll
    for (int off = 32; off > 0; off >>= 1) {
        s  += __shfl_xor(s, off);
        s2 += __shfl_xor(s2, off);
    }
    __shared__ float rs[4], rs2[4];
    const int wid = threadIdx.x >> 6, lane = threadIdx.x & 63;
    if (lane == 0) { rs[wid] = s; rs2[wid] = s2; }
    __syncthreads();
    s  = rs[0] + rs[1] + rs[2] + rs[3];
    s2 = rs2[0] + rs2[1] + rs2[2] + rs2[3];
    const float mu = s * (1.0f / 1024.0f);
    float var = s2 * (1.0f / 1024.0f) - mu * mu;
    var = fmaxf(var, 0.0f);
    const float rsg = 1.0f / sqrtf(var + 1e-5f);
    const float4 gv = ((const float4*)g)[threadIdx.x];
    const float4 bv = ((const float4*)bta)[threadIdx.x];
    ushort4v o;
    o[0] = f2b((v.x - mu) * rsg * gv.x + bv.x);
    o[1] = f2b((v.y - mu) * rsg * gv.y + bv.y);
    o[2] = f2b((v.z - mu) * rsg * gv.z + bv.z);
    o[3] = f2b((v.w - mu) * rsg * gv.w + bv.w);
    *(ushort4v*)&out[(long)tok * 1024 + threadIdx.x * 4] = o;
}

// RoPE in-place on bf16 qkv_b [2048][3072] (q: 0..1023, k: 1024..2047)
__global__ __launch_bounds__(256) void rope_kernel(unsigned short* __restrict__ qkv,
                                                   const int* __restrict__ pos)
{
    const int tok = blockIdx.x;
    const float p = (float)pos[tok];
    unsigned short* base = qkv + (long)tok * 3072;
    #pragma unroll
    for (int it = 0; it < 2; ++it) {
        const int idx = threadIdx.x + it * 256;  // (head, d<128)
        const int hh = idx >> 7, d = idx & 127;
        const float inv = exp2f((float)d * (-13.287712379549449f / 128.0f));
        const float ang = p * inv;
        const float c = cosf(ang), s = sinf(ang);
        unsigned short* qp = base + hh * 256 + d;
        {
            const float x1 = b2f(qp[0]), x2 = b2f(qp[128]);
            qp[0]   = f2b(x1 * c - x2 * s);
            qp[128] = f2b(x1 * s + x2 * c);
        }
        unsigned short* kp = qp + 1024;
        {
            const float x1 = b2f(kp[0]), x2 = b2f(kp[128]);
            kp[0]   = f2b(x1 * c - x2 * s);
            kp[128] = f2b(x1 * s + x2 * c);
        }
    }
}

// Row softmax, in-place bf16, scale 1/16; mrow is this batch's mask row.
__global__ __launch_bounds__(256) void softmax_kernel(unsigned short* __restrict__ sc,
                                                      const float* __restrict__ mrow)
{
    unsigned short* row = sc + (long)blockIdx.x * 2048;
    const int t = threadIdx.x;

    float v[8];
    const ushort4v u0 = *(const ushort4v*)&row[t * 8];
    const ushort4v u1 = *(const ushort4v*)&row[t * 8 + 4];
    #pragma unroll
    for (int i = 0; i < 4; ++i) { v[i] = b2f(u0[i]); v[4 + i] = b2f(u1[i]); }

    float mx = -3.0e38f;
    #pragma unroll
    for (int i = 0; i < 8; ++i) {
        const float m = mrow[t * 8 + i];
        v[i] = (m == 0.0f) ? -3.0e38f : v[i] * 0.0625f;
        mx = fmaxf(mx, v[i]);
    }
    #pragma unroll
    for (int off = 32; off > 0; off >>= 1) mx = fmaxf(mx, __shfl_xor(mx, off));
    __shared__ float rmx[4], rsm[4];
    const int wid = t >> 6, lane = t & 63;
    if (lane == 0) rmx[wid] = mx;
    __syncthreads();
    mx = fmaxf(fmaxf(rmx[0], rmx[1]), fmaxf(rmx[2], rmx[3]));

    float s = 0.0f;
    #pragma unroll
    for (int i = 0; i < 8; ++i) { v[i] = expf(v[i] - mx); s += v[i]; }
    #pragma unroll
    for (int off = 32; off > 0; off >>= 1) s += __shfl_xor(s, off);
    if (lane == 0) rsm[wid] = s;
    __syncthreads();
    s = rsm[0] + rsm[1] + rsm[2] + rsm[3];
    const float invs = (s > 0.0f) ? 1.0f / s : 0.0f;

    ushort4v o0, o1;
    #pragma unroll
    for (int i = 0; i < 4; ++i) { o0[i] = f2b(v[i] * invs); o1[i] = f2b(v[4 + i] * invs); }
    *(ushort4v*)&row[t * 8]     = o0;
    *(ushort4v*)&row[t * 8 + 4] = o1;
}

// lengths = sum(mask[b]); out[b] = len>0 ? h[b, len-1] : start_state
__global__ __launch_bounds__(256) void gather_kernel(const float* __restrict__ h,
    const float* __restrict__ mask, const float* __restrict__ ss, float* __restrict__ out)
{
    const int b = blockIdx.x;
    const float* mrow = mask + b * 2048;
    const int t = threadIdx.x;
    float s = 0.0f;
    #pragma unroll
    for (int i = 0; i < 8; ++i) s += mrow[t * 8 + i];
    #pragma unroll
    for (int off = 32; off > 0; off >>= 1) s += __shfl_xor(s, off);
    __shared__ float red[4];
    if ((t & 63) == 0) red[t >> 6] = s;
    __syncthreads();
    const float len = red[0] + red[1] + red[2] + red[3];
    const int L = (int)len;
    const int last = (L > 0) ? (L - 1) : 0;
    const bool has = len > 0.0f;
    const float* src = has ? (h + ((long)b * 2048 + last) * 1024) : ss;
    #pragma unroll
    for (int i = 0; i < 4; ++i) {
        const int d = t + i * 256;
        out[b * 1024 + d] = src[d];
    }
}

// ---------------------------------------------------------------------------
extern "C" void kernel_launch(void* const* d_in, const int* in_sizes, int n_in,
                              void* d_out, int out_size, void* d_ws, size_t ws_size,
                              hipStream_t stream)
{
    (void)in_sizes; (void)n_in; (void)out_size;
    const float* x      = (const float*)d_in[0];
    const int*   pos    = (const int*)d_in[1];
    const float* mask   = (const float*)d_in[2];
    const float* in_w   = (const float*)d_in[3];
    const float* in_b   = (const float*)d_in[4];
    const float* qkv_w  = (const float*)d_in[5];
    const float* o_w    = (const float*)d_in[6];
    const float* ln1_g  = (const float*)d_in[7];
    const float* ln1_b  = (const float*)d_in[8];
    const float* ffn_w1 = (const float*)d_in[9];
    const float* ffn_b1 = (const float*)d_in[10];
    const float* ffn_w2 = (const float*)d_in[11];
    const float* ffn_b2 = (const float*)d_in[12];
    const float* ln2_g  = (const float*)d_in[13];
    const float* ln2_b  = (const float*)d_in[14];
    const float* sstate = (const float*)d_in[15];
    float* out = (float*)d_out;

    // ---- workspace layout, 143.65 MB (proven safe) ----
    const size_t NEED = 143654912ull;
    if (ws_size < NEED) {
        zero_f32<<<16, 256, 0, stream>>>(out);
        return;
    }
    char* w = (char*)d_ws;
    unsigned short* wt_in  = (unsigned short*)(w);               // [1024][512]      1.0 MB
    unsigned short* wt_qkv = (unsigned short*)(w + 1048576);     // [3072][1024]/lyr 6.3 MB
    unsigned short* wt_o   = (unsigned short*)(w + 7340032);     // [1024][1024]/lyr 2.1 MB
    unsigned short* wt_f1  = (unsigned short*)(w + 9437184);     // [4096][1024]/lyr 8.4 MB
    unsigned short* wt_f2  = (unsigned short*)(w + 17825792);    // [1024][4096]/lyr 8.4 MB
    float*          hbuf   = (float*)(w + 26214400);             // [8192][1024] f32 33.5 MB
    unsigned short* xn_bf  = (unsigned short*)(w + 59768832);    // [8192][1024]     16.8 MB
    unsigned short* ao_bf  = (unsigned short*)(w + 76546048);    // [8192][1024]     16.8 MB
    unsigned short* qkv_b  = (unsigned short*)(w + 93323264);    // [2048][3072]/b   12.6 MB
    unsigned short* vT_b   = (unsigned short*)(w + 105906176);   // [4][256][2048]/b  4.2 MB
    unsigned short* scmid  = (unsigned short*)(w + 110100480);   // [4][2048][2048]  33.5 MB
    unsigned short* x_bf   = ao_bf;                              // [8192][512], dead before ao live
    unsigned short* mid_bf = (unsigned short*)(w + 76546048);    // FFN mid aliases ao/qkv/vT/scmid

    const dim3 tb(32, 8);

    transpose_cast_f32<<<dim3(32, 16), tb, 0, stream>>>(in_w, wt_in, 512, 1024);
    cast_f32_bf16<<<4096, 256, 0, stream>>>(x, x_bf);

    // h = x @ in_w + in_b   (f32)  M=8192 N=1024 K=512 — 256 blocks
    gemm9<256, 128><<<dim3(8, 32, 1), 512, 0, stream>>>(x_bf, wt_in, hbuf, nullptr, in_b,
        512, 512, 512, 1024, 1, 0, 0, 0, 0, 0, 0, 0);

    for (int l = 0; l < 2; ++l) {
        transpose_cast_f32<<<dim3(96, 32),  tb, 0, stream>>>(qkv_w  + (long)l * 3145728, wt_qkv, 1024, 3072);
        transpose_cast_f32<<<dim3(32, 32),  tb, 0, stream>>>(o_w    + (long)l * 1048576, wt_o,   1024, 1024);
        transpose_cast_f32<<<dim3(128, 32), tb, 0, stream>>>(ffn_w1 + (long)l * 4194304, wt_f1,  1024, 4096);
        transpose_cast_f32<<<dim3(32, 128), tb, 0, stream>>>(ffn_w2 + (long)l * 4194304, wt_f2,  4096, 1024);

        ln_kernel<<<8192, 256, 0, stream>>>(hbuf, ln1_g + l * 1024, ln1_b + l * 1024, xn_bf);

        for (int b = 0; b < 4; ++b) {
            // qkv: Q,K -> qkv_b; V -> vT_b directly (mode 5, Vt via Cf param)
            // M=2048 N=3072 K=1024 — 192 blocks
            gemm9<128, 256><<<dim3(12, 16, 1), 512, 0, stream>>>(xn_bf + (long)b * 2097152, wt_qkv,
                (float*)vT_b, qkv_b, nullptr, 1024, 1024, 1024, 3072, 1, 0, 0, 0, 0, 0, 0, 5);
            rope_kernel<<<2048, 256, 0, stream>>>(qkv_b, pos + b * 2048);
            // scores[h] = q @ k^T  (raw; softmax applies 1/16)  K=256 — 256 blocks
            gemm9<256, 256><<<dim3(8, 8, 4), 512, 0, stream>>>(qkv_b, qkv_b + 1024,
                nullptr, scmid, nullptr, 256, 3072, 3072, 2048,
                1, 256l, 0, 256l, 0, 4194304l, 0, 2);
            softmax_kernel<<<8192, 256, 0, stream>>>(scmid, mask + b * 2048);
            // ao[b][m][h*256+d] = P @ V — BK=64 dbuf: 512 blocks, 5 blocks/CU
            gemm64<<<dim3(4, 32, 4), 256, 0, stream>>>(scmid, vT_b,
                ao_bf + (long)b * 2097152, 2048, 2048, 2048, 1024,
                4194304l, 524288l, 256l);
        }
        // h += attn_out @ o_w   M=8192 N=1024 K=1024 — 256 blocks
        gemm9<256, 128><<<dim3(8, 32, 1), 512, 0, stream>>>(ao_bf, wt_o,
            hbuf, nullptr, nullptr, 1024, 1024, 1024, 1024, 1, 0, 0, 0, 0, 0, 0, 1);

        ln_kernel<<<8192, 256, 0, stream>>>(hbuf, ln2_g + l * 1024, ln2_b + l * 1024, xn_bf);

        // mid = gelu(LN2(h) @ w1 + b1)  (bf16)  M=8192 N=4096 K=1024 — 512 blocks
        gemm9<256, 256><<<dim3(16, 32, 1), 512, 0, stream>>>(xn_bf, wt_f1,
            nullptr, mid_bf, ffn_b1 + l * 4096, 1024, 1024, 1024, 4096, 1, 0, 0, 0, 0, 0, 0, 3);
        // h += mid @ w2 + b2   M=8192 N=1024 K=4096 — 256 blocks
        gemm9<256, 128><<<dim3(8, 32, 1), 512, 0, stream>>>(mid_bf, wt_f2,
            hbuf, nullptr, ffn_b2 + l * 1024, 4096, 4096, 4096, 1024, 1, 0, 0, 0, 0, 0, 0, 1);
    }

    gather_kernel<<<4, 256, 0, stream>>>(hbuf, mask, sstate, out);
}